// Round 13
// baseline (141.808 us; speedup 1.0000x reference)
//
#include <hip/hip_runtime.h>
#include <cstdint>
#include <cstddef>

#define N_CLS 80
#define TOPK 1000
#define POOL_N 2048
#define MCAP 512
#define BD 1024
#define DTB 128
#define NBLK 197         // ceil(25200 / 128)
#define SLICE 32         // slots per (class, block); Binom(128,1/80) P(ovf)~1e-25
#define LDSB_STRIDE 10   // u64 stride: 80B rows, 16B-aligned

// ---------------- K1: decode + score + hierarchical binning ----------------
// R13 = R11 (113.6 best) + __launch_bounds__(128,1). R12 post-mortem: three
// store-layout theories dead; the surviving model is MLP starvation — at
// VGPR_Count=52 the compiler batches the 20 cls dwordx4 loads to preserve
// occupancy we never use (197 blocks < 256 CUs => grid-limited). Lifting the
// cap lets all 20 loads stay in flight per thread (matches R5>R10 evidence).
__global__ __launch_bounds__(DTB, 1) void decode_kernel(
    const float* __restrict__ reg, const float* __restrict__ obj,
    const float* __restrict__ cls, const float* __restrict__ grid,
    const float* __restrict__ anch, const float* __restrict__ strd,
    float* __restrict__ boxes, uint2* __restrict__ scs,
    int* __restrict__ cnts, uint2* __restrict__ gpool2, int N) {
  __shared__ int hcnt[N_CLS];
  const int blk = blockIdx.x;
  const int tid = threadIdx.x;
  const int i = blk * DTB + tid;

  if (tid < N_CLS) hcnt[tid] = 0;
  __syncthreads();

  const bool valid = (i < N);
  float best = -1.0f;
  int bc = 0;

  if (valid) {
    const float4 r = ((const float4*)reg)[i];
    const float2 g = ((const float2*)grid)[i];
    const float2 aw = ((const float2*)anch)[i];
    const float st = strd[i];

    float cx = (1.0f / (1.0f + expf(-r.x)) + g.x) * st;
    float cy = (1.0f / (1.0f + expf(-r.y)) + g.y) * st;
    float w = expf(r.z) * aw.x;
    float h = expf(r.w) * aw.y;
    float b0 = fminf(fmaxf((cx - 0.5f * w) / 640.0f, 0.0f), 1.0f);
    float b1 = fminf(fmaxf((cy - 0.5f * h) / 640.0f, 0.0f), 1.0f);
    float b2 = fminf(fmaxf((cx + 0.5f * w) / 640.0f, 0.0f), 1.0f);
    float b3 = fminf(fmaxf((cy + 0.5f * h) / 640.0f, 0.0f), 1.0f);
    float4 bo; bo.x = b0; bo.y = b1; bo.z = b2; bo.w = b3;
    ((float4*)boxes)[i] = bo;

    const float4* cr = (const float4*)cls + (size_t)i * 20;
    float4 x[20];
#pragma unroll
    for (int q = 0; q < 20; ++q) x[q] = cr[q];

    // max: fmaxf exact & order-independent (no NaNs) => tree == chain
    float4 m4 = x[0];
#pragma unroll
    for (int q = 1; q < 20; ++q) {
      m4.x = fmaxf(m4.x, x[q].x); m4.y = fmaxf(m4.y, x[q].y);
      m4.z = fmaxf(m4.z, x[q].z); m4.w = fmaxf(m4.w, x[q].w);
    }
    float mx = fmaxf(fmaxf(m4.x, m4.y), fmaxf(m4.z, m4.w));

    // e_c = expf(x_c - mx) once, in place (deterministic => bit-exact)
#pragma unroll
    for (int q = 0; q < 20; ++q) {
      x[q].x = expf(x[q].x - mx); x[q].y = expf(x[q].y - mx);
      x[q].z = expf(x[q].z - mx); x[q].w = expf(x[q].w - mx);
    }

    // s: strict left fold c=0..79 (matches verified reduction order)
    float s = 0.0f;
#pragma unroll
    for (int q = 0; q < 20; ++q) {
      s += x[q].x; s += x[q].y; s += x[q].z; s += x[q].w;
    }

    float sig = 1.0f / (1.0f + expf(-obj[i]));

    // first-occurrence argmax of q = sig*(e/s), identical exprs & order
#pragma unroll
    for (int q = 0; q < 20; ++q) {
      float q0 = sig * (x[q].x / s);
      if (q0 > best) { best = q0; bc = 4 * q + 0; }
      float q1 = sig * (x[q].y / s);
      if (q1 > best) { best = q1; bc = 4 * q + 1; }
      float q2 = sig * (x[q].z / s);
      if (q2 > best) { best = q2; bc = 4 * q + 2; }
      float q3 = sig * (x[q].w / s);
      if (q3 > best) { best = q3; bc = 4 * q + 3; }
    }
    scs[i] = make_uint2(__float_as_uint(best), (unsigned)bc);
  }

  // binning: block-local LDS slot, scattered store of real entries (R5 form)
  const bool pos = valid && (best >= 0.001f);
  int slot = -1;
  if (pos) slot = atomicAdd(&hcnt[bc], 1);
  __syncthreads();
  if (tid < N_CLS) cnts[blk * N_CLS + tid] = min(hcnt[tid], SLICE);  // blk-major
  if (pos && slot < SLICE)
    gpool2[((size_t)bc * NBLK + blk) * SLICE + slot] =
        make_uint2(__float_as_uint(best), (unsigned)i);
}

// ---- K2: slice gather + rank sort + fillers + build + staged greedy + out -
// Jacobi replaced with EXACT staged greedy: stage w (executed by wave w)
// finalizes rows [64w, 64w+64) after km[0..w-1] are final. Suppressor matrix
// is strictly lower-triangular, so evaluating blocks in order + an in-wave
// ffs/ballot loop (iterations = #kept rows in the block) IS the sequential
// greedy => bit-identical keep mask. <=8 barriers total (vs 1-2/Jacobi round).
__global__ __launch_bounds__(BD, 4) void nms_kernel(
    const float* __restrict__ boxes, const uint2* __restrict__ scs,
    const int* __restrict__ cnts, const uint2* __restrict__ gpool2,
    float* __restrict__ out, int N) {
  const int c = blockIdx.x;
  const int tid = threadIdx.x;

  __shared__ uint2 pool[POOL_N];                     // 16 KB
  __shared__ float svals[TOPK];                      // 4 KB
  __shared__ int sidx[TOPK];                         // 4 KB
  __shared__ __align__(16) float4 bxyz[TOPK];        // 16 KB
  __shared__ __align__(16) unsigned long long ldsB[MCAP * LDSB_STRIDE];  // 40 KB
  __shared__ unsigned char kp[TOPK];                 // fallback only
  __shared__ unsigned long long kmw_lds[8];
  __shared__ int wsum[BD / 64 + 1];
  __shared__ int pref[NBLK + 1];

  // clamped prefix over 197 block-counts by wave 0 (shuffle scan).
  // min(carry+v, POOL_N) with UNCLAMPED carry == sequential clamp (monotone).
  if (tid < 64) {
    int carry = 0;
    if (tid == 0) pref[0] = 0;
    for (int ch = 0; ch < (NBLK + 63) / 64; ++ch) {
      int b = ch * 64 + tid;
      int v = (b < NBLK) ? cnts[b * N_CLS + c] : 0;   // blk-major gather
#pragma unroll
      for (int s = 1; s < 64; s <<= 1) {
        int u = __shfl_up(v, s, 64);
        if (tid >= (unsigned)s) v += u;
      }
      if (b < NBLK) pref[b + 1] = min(carry + v, POOL_N);
      carry += __shfl(v, 63, 64);
    }
  }
  if (tid < 8) kmw_lds[tid] = 0ULL;
  __syncthreads();
  const int cnt = pref[NBLK];
  const int m = min(cnt, TOPK);

  // gather: pool[t] = entry t in (blk-major, slot) order via binary search
  const uint2* gp = gpool2 + (size_t)c * NBLK * SLICE;
  for (int t = tid; t < cnt; t += BD) {
    int lo = 0, hi = NBLK;
    while (hi - lo > 1) {
      int mid = (lo + hi) >> 1;
      if (t >= pref[mid]) lo = mid; else hi = mid;
    }
    pool[t] = gp[(size_t)lo * SLICE + (t - pref[lo])];
  }
  __syncthreads();

  // rank sort: value desc, ties -> index asc (== jax.lax.top_k order);
  // strict total order (unique indices) => independent of pool fill order.
  for (int e = tid; e < cnt; e += BD) {
    uint2 me = pool[e];
    float v = __uint_as_float(me.x);
    int idx = (int)me.y;
    int r = 0;
#pragma unroll 8
    for (int k = 0; k < cnt; ++k) {
      uint2 q = pool[k];
      float vk = __uint_as_float(q.x);
      r += (int)((vk > v) || (vk == v && (int)q.y < idx));
    }
    if (r < TOPK) { svals[r] = v; sidx[r] = idx; }
  }
  __syncthreads();

  // fillers: lowest-index non-matching anchors, ascending; one 1024-pass
  // suffices (positives in any prefix <= m <= 1000 < 1024).
  const int M = TOPK - m;
  if (M > 0) {
    int i = tid;
    bool f = false;
    if (i < N) {
      uint2 sc = scs[i];
      f = !((int)sc.y == c && __uint_as_float(sc.x) >= 0.001f);
    }
    unsigned long long mk = __ballot(f ? 1 : 0);
    int lane = tid & 63, wv = tid >> 6;
    int pre = __popcll(mk & ((1ULL << lane) - 1ULL));
    if (lane == 0) wsum[wv] = __popcll(mk);
    __syncthreads();
    if (tid == 0) {
      int acc = 0;
      for (int wq = 0; wq < BD / 64; ++wq) { int t2 = wsum[wq]; wsum[wq] = acc; acc += t2; }
    }
    __syncthreads();
    int pos = wsum[wv] + pre;
    if (f && pos < M) sidx[m + pos] = i;
  }
  __syncthreads();

  // gather boxes into LDS
  const float4* bf4 = (const float4*)boxes;
  for (int t = tid; t < TOPK; t += BD) bxyz[t] = bf4[sidx[t]];
  __syncthreads();

  const int W = (m + 63) >> 6;
  const bool fast = (m > 0) && (m <= MCAP);

  if (fast) {
    // build TRANSPOSED lower-triangle mask: row j, word w = bits of i<j with
    // iou(i,j)>0.6 (IoU symmetric in (i,j) => bits bit-identical to greedy)
    const int tasks = m * W;
    for (int q = tid; q < tasks; q += BD) {
      int w = q / m;
      int j = q - w * m;
      unsigned long long bits = 0ULL;
      if (w <= (j >> 6)) {
        float4 jb = bxyz[j];
        float aj = (jb.z - jb.x) * (jb.w - jb.y);
        int i0 = w << 6, iend = min(i0 + 64, j);  // i < j strictly
        for (int i = i0; i < iend; ++i) {
          float4 ib = bxyz[i];
          float ai = (ib.z - ib.x) * (ib.w - ib.y);
          float xx1 = fmaxf(ib.x, jb.x), yy1 = fmaxf(ib.y, jb.y);
          float xx2 = fminf(ib.z, jb.z), yy2 = fminf(ib.w, jb.w);
          float ww = fmaxf(1e-28f, xx2 - xx1), hh = fmaxf(1e-28f, yy2 - yy1);
          float inter = ww * hh;
          float iou = inter / (ai + aj - inter + 1e-14f);
          if (iou > 0.6f) bits |= (1ULL << (i - i0));
        }
      }
      ldsB[(size_t)j * LDSB_STRIDE + w] = bits;
    }
    __syncthreads();

    // my suppressor row in 16 VGPRs
    ulonglong2 ta, tb, tc, td;
    ta = tb = tc = td = make_ulonglong2(0ULL, 0ULL);
    if (tid < m) {
      const ulonglong2* rp = (const ulonglong2*)&ldsB[(size_t)tid * LDSB_STRIDE];
      ta = rp[0]; tb = rp[1]; tc = rp[2]; td = rp[3];
    }
    __syncthreads();

    // staged greedy: supAcc accumulates (word_u & km[u]) after each stage.
    // Wave w resolves its 64 rows with an ffs/ballot loop; a row picked at
    // bit b is kept iff alive (no kept suppressor among finalized rows);
    // skipped rows are dead => exact sequential-greedy semantics.
    unsigned long long supAcc = 0ULL;
#define GREEDY_STAGE(w, word)                                                \
    if (((w) << 6) < m) {                                                    \
      if ((tid >> 6) == (w)) {                                               \
        bool alive = (tid < m) && (supAcc == 0ULL);                          \
        unsigned long long bb = (word);                                      \
        unsigned long long kmw = 0ULL, done = 0ULL;                          \
        for (;;) {                                                           \
          unsigned long long kb = __ballot(alive) & ~done;                   \
          if (!kb) break;                                                    \
          int b = __ffsll((long long)kb) - 1;                                \
          kmw |= (1ULL << b);                                                \
          done = (b >= 63) ? ~0ULL : ((2ULL << b) - 1ULL);                   \
          if ((bb >> b) & 1ULL) alive = false;                               \
        }                                                                    \
        if ((tid & 63) == 0) kmw_lds[w] = kmw;                               \
      }                                                                      \
      __syncthreads();                                                       \
      supAcc |= (word) & kmw_lds[w];                                         \
    }
    GREEDY_STAGE(0, ta.x)
    GREEDY_STAGE(1, ta.y)
    GREEDY_STAGE(2, tb.x)
    GREEDY_STAGE(3, tb.y)
    GREEDY_STAGE(4, tc.x)
    GREEDY_STAGE(5, tc.y)
    GREEDY_STAGE(6, td.x)
    GREEDY_STAGE(7, td.y)
#undef GREEDY_STAGE
  } else {
    // fallback (m == 0 or m > MCAP): serial barrier loop — always correct
    for (int t = tid; t < TOPK; t += BD) kp[t] = (t < m) ? 1 : 0;
    __syncthreads();
    for (int i = 0; i < m; ++i) {
      if (kp[i]) {
        float4 rb = bxyz[i];
        float ai = (rb.z - rb.x) * (rb.w - rb.y);
        for (int j = i + 1 + tid; j < m; j += BD) {
          if (kp[j]) {
            float4 jb = bxyz[j];
            float aj = (jb.z - jb.x) * (jb.w - jb.y);
            float xx1 = fmaxf(rb.x, jb.x), yy1 = fmaxf(rb.y, jb.y);
            float xx2 = fminf(rb.z, jb.z), yy2 = fminf(rb.w, jb.w);
            float ww = fmaxf(1e-28f, xx2 - xx1), hh = fmaxf(1e-28f, yy2 - yy1);
            float inter = ww * hh;
            float iou = inter / (ai + aj - inter + 1e-14f);
            if (iou > 0.6f) kp[j] = 0;
          }
        }
      }
      __syncthreads();
    }
  }

  // outputs: boxes [80,1000,4], scores*keep [80,1000], keep [80,1000]
  float* outB = out;
  float* outS = out + N_CLS * TOPK * 4;
  float* outK = outS + N_CLS * TOPK;
  for (int t = tid; t < TOPK; t += BD) {
    float k = 0.0f;
    if (t < m)
      k = fast ? (float)((kmw_lds[t >> 6] >> (t & 63)) & 1ULL)
               : (float)kp[t];
    float v = (t < m) ? svals[t] : -1.0f;
    ((float4*)outB)[c * TOPK + t] = bxyz[t];
    outS[c * TOPK + t] = v * k;
    outK[c * TOPK + t] = k;
  }
}

extern "C" void kernel_launch(void* const* d_in, const int* in_sizes, int n_in,
                              void* d_out, int out_size, void* d_ws, size_t ws_size,
                              hipStream_t stream) {
  const float* reg  = (const float*)d_in[0];
  const float* obj  = (const float*)d_in[1];
  const float* cls  = (const float*)d_in[2];
  const float* grid = (const float*)d_in[3];
  const float* anch = (const float*)d_in[4];
  const float* strd = (const float*)d_in[5];
  const int N = in_sizes[0] / 4;  // 25200

  char* w8 = (char*)d_ws;
  size_t off = 0;
  float* boxes  = (float*)(w8 + off); off += (size_t)N * 16;
  uint2* scs    = (uint2*)(w8 + off); off += (size_t)N * 8;
  int*   cnts   = (int*)(w8 + off);   off += (size_t)NBLK * N_CLS * 4;
  uint2* gpool2 = (uint2*)(w8 + off); off += (size_t)N_CLS * NBLK * SLICE * 8;
  float* out = (float*)d_out;

  decode_kernel<<<NBLK, DTB, 0, stream>>>(
      reg, obj, cls, grid, anch, strd, boxes, scs, cnts, gpool2, N);
  nms_kernel<<<N_CLS, BD, 0, stream>>>(boxes, scs, cnts, gpool2, out, N);
}

// Round 14
// 112.895 us; speedup vs baseline: 1.2561x; 1.2561x over previous
//
#include <hip/hip_runtime.h>
#include <cstdint>
#include <cstddef>

#define N_CLS 80
#define TOPK 1000
#define POOL_N 2048
#define MCAP 512
#define BD 1024
#define DTB 128
#define NBLK 197         // ceil(25200 / 128)
#define SLICE 32         // slots per (class, block); Binom(128,1/80) P(ovf)~1e-25
#define LDSB_STRIDE 10   // u64 stride: 80B rows, 16B-aligned

// ---------------- K1: decode + score + hierarchical binning ----------------
// (R11 verbatim — best measured 113.6; R13's launch_bounds(,1) was neutral)
__global__ __launch_bounds__(DTB) void decode_kernel(
    const float* __restrict__ reg, const float* __restrict__ obj,
    const float* __restrict__ cls, const float* __restrict__ grid,
    const float* __restrict__ anch, const float* __restrict__ strd,
    float* __restrict__ boxes, uint2* __restrict__ scs,
    int* __restrict__ cnts, uint2* __restrict__ gpool2, int N) {
  __shared__ int hcnt[N_CLS];
  const int blk = blockIdx.x;
  const int tid = threadIdx.x;
  const int i = blk * DTB + tid;

  if (tid < N_CLS) hcnt[tid] = 0;
  __syncthreads();

  const bool valid = (i < N);
  float best = -1.0f;
  int bc = 0;

  if (valid) {
    const float4 r = ((const float4*)reg)[i];
    const float2 g = ((const float2*)grid)[i];
    const float2 aw = ((const float2*)anch)[i];
    const float st = strd[i];

    float cx = (1.0f / (1.0f + expf(-r.x)) + g.x) * st;
    float cy = (1.0f / (1.0f + expf(-r.y)) + g.y) * st;
    float w = expf(r.z) * aw.x;
    float h = expf(r.w) * aw.y;
    float b0 = fminf(fmaxf((cx - 0.5f * w) / 640.0f, 0.0f), 1.0f);
    float b1 = fminf(fmaxf((cy - 0.5f * h) / 640.0f, 0.0f), 1.0f);
    float b2 = fminf(fmaxf((cx + 0.5f * w) / 640.0f, 0.0f), 1.0f);
    float b3 = fminf(fmaxf((cy + 0.5f * h) / 640.0f, 0.0f), 1.0f);
    float4 bo; bo.x = b0; bo.y = b1; bo.z = b2; bo.w = b3;
    ((float4*)boxes)[i] = bo;

    const float4* cr = (const float4*)cls + (size_t)i * 20;
    float4 x[20];
#pragma unroll
    for (int q = 0; q < 20; ++q) x[q] = cr[q];

    // max: fmaxf exact & order-independent (no NaNs) => tree == chain
    float4 m4 = x[0];
#pragma unroll
    for (int q = 1; q < 20; ++q) {
      m4.x = fmaxf(m4.x, x[q].x); m4.y = fmaxf(m4.y, x[q].y);
      m4.z = fmaxf(m4.z, x[q].z); m4.w = fmaxf(m4.w, x[q].w);
    }
    float mx = fmaxf(fmaxf(m4.x, m4.y), fmaxf(m4.z, m4.w));

    // e_c = expf(x_c - mx) once, in place (deterministic => bit-exact)
#pragma unroll
    for (int q = 0; q < 20; ++q) {
      x[q].x = expf(x[q].x - mx); x[q].y = expf(x[q].y - mx);
      x[q].z = expf(x[q].z - mx); x[q].w = expf(x[q].w - mx);
    }

    // s: strict left fold c=0..79 (matches verified reduction order)
    float s = 0.0f;
#pragma unroll
    for (int q = 0; q < 20; ++q) {
      s += x[q].x; s += x[q].y; s += x[q].z; s += x[q].w;
    }

    float sig = 1.0f / (1.0f + expf(-obj[i]));

    // first-occurrence argmax of q = sig*(e/s), identical exprs & order
#pragma unroll
    for (int q = 0; q < 20; ++q) {
      float q0 = sig * (x[q].x / s);
      if (q0 > best) { best = q0; bc = 4 * q + 0; }
      float q1 = sig * (x[q].y / s);
      if (q1 > best) { best = q1; bc = 4 * q + 1; }
      float q2 = sig * (x[q].z / s);
      if (q2 > best) { best = q2; bc = 4 * q + 2; }
      float q3 = sig * (x[q].w / s);
      if (q3 > best) { best = q3; bc = 4 * q + 3; }
    }
    scs[i] = make_uint2(__float_as_uint(best), (unsigned)bc);
  }

  const bool pos = valid && (best >= 0.001f);
  int slot = -1;
  if (pos) slot = atomicAdd(&hcnt[bc], 1);
  __syncthreads();
  if (tid < N_CLS) cnts[blk * N_CLS + tid] = min(hcnt[tid], SLICE);  // blk-major
  if (pos && slot < SLICE)
    gpool2[((size_t)bc * NBLK + blk) * SLICE + slot] =
        make_uint2(__float_as_uint(best), (unsigned)i);
}

__device__ __forceinline__ unsigned long long kinit(int w, int m) {
  int lo = w << 6;
  return (m <= lo) ? 0ULL : ((m - lo >= 64) ? ~0ULL : ((1ULL << (m - lo)) - 1ULL));
}

// ---- K2: latency-overlapped NMS (R14) -------------------------------------
// R13 post-mortem: nms directly measured ~38us at R11 while compute models
// give ~10 => serial phase latency (8 dependent phases x cold-miss each,
// 1 block/CU, nothing co-resident to hide it). This round collapses the
// chain: (A) all independent loads prefetched together (cnts->LDS coop;
// per-thread filler scs/box -> regs), (B) pool gather issues the dependent
// boxes[pool.y] load into regs, consumed AFTER the rank loop => the old
// serial bxyz-gather phase is deleted (sidx dead, removed). Greedy = R11
// Jacobi (R13 staged greedy reverted: measured +28us).
__global__ __launch_bounds__(BD) void nms_kernel(
    const float* __restrict__ boxes, const uint2* __restrict__ scs,
    const int* __restrict__ cnts, const uint2* __restrict__ gpool2,
    float* __restrict__ out, int N) {
  const int c = blockIdx.x;
  const int tid = threadIdx.x;

  __shared__ uint2 pool[POOL_N];                     // 16 KB
  __shared__ float svals[TOPK];                      // 4 KB
  __shared__ __align__(16) float4 bxyz[TOPK];        // 16 KB
  __shared__ __align__(16) unsigned long long ldsB[MCAP * LDSB_STRIDE];  // 40 KB
  __shared__ unsigned char kp[TOPK];                 // fallback only
  __shared__ __align__(16) unsigned long long kmbuf[2][8];
  __shared__ int wsum[BD / 64 + 1];
  __shared__ int pref[NBLK + 1];
  __shared__ int cntl[NBLK];

  // ---- phase A: all independent prefetches issued together ----
  for (int b = tid; b < NBLK; b += BD) cntl[b] = cnts[b * N_CLS + c];
  const uint2 mySc = scs[tid];                 // filler predicate (tid<1024<=N)
  const float4 myBox = ((const float4*)boxes)[tid];  // filler box
  __syncthreads();

  // wave-0 clamped prefix from LDS (min(carry+v,POOL_N) w/ unclamped carry
  // == sequential clamp; monotone)
  if (tid < 64) {
    int carry = 0;
    if (tid == 0) pref[0] = 0;
    for (int ch = 0; ch < (NBLK + 63) / 64; ++ch) {
      int b = ch * 64 + tid;
      int v = (b < NBLK) ? cntl[b] : 0;
#pragma unroll
      for (int s = 1; s < 64; s <<= 1) {
        int u = __shfl_up(v, s, 64);
        if (tid >= (unsigned)s) v += u;
      }
      if (b < NBLK) pref[b + 1] = min(carry + v, POOL_N);
      carry += __shfl(v, 63, 64);
    }
  }
  __syncthreads();
  const int cnt = pref[NBLK];
  const int m = min(cnt, TOPK);

  // ---- phase C: pool gather + dependent box load into registers ----
  const uint2* gp = gpool2 + (size_t)c * NBLK * SLICE;
  const float4* bf4 = (const float4*)boxes;
  uint2 me[POOL_N / BD];
  float4 boxE[POOL_N / BD];
#pragma unroll
  for (int u = 0; u < POOL_N / BD; ++u) {
    int t = tid + u * BD;
    if (t < cnt) {
      int lo = 0, hi = NBLK;
      while (hi - lo > 1) {
        int mid = (lo + hi) >> 1;
        if (t >= pref[mid]) lo = mid; else hi = mid;
      }
      uint2 e = gp[(size_t)lo * SLICE + (t - pref[lo])];
      pool[t] = e;
      me[u] = e;
      boxE[u] = bf4[e.y];                      // issued now, used post-sort
    }
  }
  __syncthreads();

  // ---- phase D: rank sort; write svals[r] and bxyz[r] directly ----
  // value desc, ties -> index asc (== jax.lax.top_k order); strict total
  // order (unique indices) => independent of pool fill order.
#pragma unroll
  for (int u = 0; u < POOL_N / BD; ++u) {
    int e = tid + u * BD;
    if (e < cnt) {
      float v = __uint_as_float(me[u].x);
      int idx = (int)me[u].y;
      int r = 0;
#pragma unroll 8
      for (int k = 0; k < cnt; ++k) {
        uint2 q = pool[k];
        float vk = __uint_as_float(q.x);
        r += (int)((vk > v) || (vk == v && (int)q.y < idx));
      }
      if (r < TOPK) { svals[r] = v; bxyz[r] = boxE[u]; }
    }
  }

  // ---- phase E: fillers write bxyz[m+pos] from registers ----
  // lowest-index non-matching anchors, ascending; one 1024-pass suffices
  // (positives in any prefix <= m <= 1000 < 1024). Disjoint bxyz range
  // [m,TOPK) vs sort's [0,m) => no barrier needed between D and E.
  const int M = TOPK - m;
  if (M > 0) {
    bool f = !((int)mySc.y == c && __uint_as_float(mySc.x) >= 0.001f);
    unsigned long long mk = __ballot(f ? 1 : 0);
    int lane = tid & 63, wv = tid >> 6;
    int pre = __popcll(mk & ((1ULL << lane) - 1ULL));
    if (lane == 0) wsum[wv] = __popcll(mk);
    __syncthreads();
    if (tid == 0) {
      int acc = 0;
      for (int wq = 0; wq < BD / 64; ++wq) { int t2 = wsum[wq]; wsum[wq] = acc; acc += t2; }
    }
    __syncthreads();
    int pos = wsum[wv] + pre;
    if (f && pos < M) bxyz[m + pos] = myBox;
  }
  __syncthreads();

  const int W = (m + 63) >> 6;
  const bool fast = (m > 0) && (m <= MCAP);
  int cur = 0;

  if (fast) {
    // build TRANSPOSED lower-triangle mask: row j, word w = bits of i<j with
    // iou(i,j)>0.6 (IoU symmetric in (i,j) => bits bit-identical to greedy)
    const int tasks = m * W;
    for (int q = tid; q < tasks; q += BD) {
      int w = q / m;
      int j = q - w * m;
      unsigned long long bits = 0ULL;
      if (w <= (j >> 6)) {
        float4 jb = bxyz[j];
        float aj = (jb.z - jb.x) * (jb.w - jb.y);
        int i0 = w << 6, iend = min(i0 + 64, j);  // i < j strictly
        for (int i = i0; i < iend; ++i) {
          float4 ib = bxyz[i];
          float ai = (ib.z - ib.x) * (ib.w - ib.y);
          float xx1 = fmaxf(ib.x, jb.x), yy1 = fmaxf(ib.y, jb.y);
          float xx2 = fminf(ib.z, jb.z), yy2 = fminf(ib.w, jb.w);
          float ww = fmaxf(1e-28f, xx2 - xx1), hh = fmaxf(1e-28f, yy2 - yy1);
          float inter = ww * hh;
          float iou = inter / (ai + aj - inter + 1e-14f);
          if (iou > 0.6f) bits |= (1ULL << (i - i0));
        }
      }
      ldsB[(size_t)j * LDSB_STRIDE + w] = bits;
    }
    __syncthreads();

    // cache my suppressor row in 16 VGPRs; init km = all m rows kept
    ulonglong2 ta, tb, tc, td;
    ta = tb = tc = td = make_ulonglong2(0ULL, 0ULL);
    if (tid < m) {
      const ulonglong2* rp = (const ulonglong2*)&ldsB[(size_t)tid * LDSB_STRIDE];
      ta = rp[0]; tb = rp[1]; tc = rp[2]; td = rp[3];
    }
    if (tid < 8) kmbuf[0][tid] = kinit(tid, m);
    __syncthreads();

    // Jacobi sweeps to fixpoint (exact: unique fixpoint == greedy mask)
    for (;;) {
      bool keep = false;
      if (tid < m) {
        unsigned long long sup =
            (ta.x & kmbuf[cur][0]) | (ta.y & kmbuf[cur][1]) |
            (tb.x & kmbuf[cur][2]) | (tb.y & kmbuf[cur][3]) |
            (tc.x & kmbuf[cur][4]) | (tc.y & kmbuf[cur][5]) |
            (td.x & kmbuf[cur][6]) | (td.y & kmbuf[cur][7]);
        keep = (sup == 0ULL);
      }
      bool old = (tid < m) &&
                 ((kmbuf[cur][tid >> 6] >> (tid & 63)) & 1ULL);
      unsigned long long bl = __ballot(keep ? 1 : 0);
      int wv = tid >> 6;
      if ((tid & 63) == 0 && wv < 8) kmbuf[cur ^ 1][wv] = bl;
      int any = __syncthreads_or((int)(keep != old));
      cur ^= 1;
      if (!any) break;
    }
  } else {
    // fallback (m == 0 or m > MCAP): serial barrier loop — always correct
    for (int t = tid; t < TOPK; t += BD) kp[t] = (t < m) ? 1 : 0;
    __syncthreads();
    for (int i = 0; i < m; ++i) {
      if (kp[i]) {
        float4 rb = bxyz[i];
        float ai = (rb.z - rb.x) * (rb.w - rb.y);
        for (int j = i + 1 + tid; j < m; j += BD) {
          if (kp[j]) {
            float4 jb = bxyz[j];
            float aj = (jb.z - jb.x) * (jb.w - jb.y);
            float xx1 = fmaxf(rb.x, jb.x), yy1 = fmaxf(rb.y, jb.y);
            float xx2 = fminf(rb.z, jb.z), yy2 = fminf(rb.w, jb.w);
            float ww = fmaxf(1e-28f, xx2 - xx1), hh = fmaxf(1e-28f, yy2 - yy1);
            float inter = ww * hh;
            float iou = inter / (ai + aj - inter + 1e-14f);
            if (iou > 0.6f) kp[j] = 0;
          }
        }
      }
      __syncthreads();
    }
  }

  // outputs: boxes [80,1000,4], scores*keep [80,1000], keep [80,1000]
  float* outB = out;
  float* outS = out + N_CLS * TOPK * 4;
  float* outK = outS + N_CLS * TOPK;
  for (int t = tid; t < TOPK; t += BD) {
    float k = 0.0f;
    if (t < m)
      k = fast ? (float)((kmbuf[cur][t >> 6] >> (t & 63)) & 1ULL)
               : (float)kp[t];
    float v = (t < m) ? svals[t] : -1.0f;
    ((float4*)outB)[c * TOPK + t] = bxyz[t];
    outS[c * TOPK + t] = v * k;
    outK[c * TOPK + t] = k;
  }
}

extern "C" void kernel_launch(void* const* d_in, const int* in_sizes, int n_in,
                              void* d_out, int out_size, void* d_ws, size_t ws_size,
                              hipStream_t stream) {
  const float* reg  = (const float*)d_in[0];
  const float* obj  = (const float*)d_in[1];
  const float* cls  = (const float*)d_in[2];
  const float* grid = (const float*)d_in[3];
  const float* anch = (const float*)d_in[4];
  const float* strd = (const float*)d_in[5];
  const int N = in_sizes[0] / 4;  // 25200

  char* w8 = (char*)d_ws;
  size_t off = 0;
  float* boxes  = (float*)(w8 + off); off += (size_t)N * 16;
  uint2* scs    = (uint2*)(w8 + off); off += (size_t)N * 8;
  int*   cnts   = (int*)(w8 + off);   off += (size_t)NBLK * N_CLS * 4;
  uint2* gpool2 = (uint2*)(w8 + off); off += (size_t)N_CLS * NBLK * SLICE * 8;
  float* out = (float*)d_out;

  decode_kernel<<<NBLK, DTB, 0, stream>>>(
      reg, obj, cls, grid, anch, strd, boxes, scs, cnts, gpool2, N);
  nms_kernel<<<N_CLS, BD, 0, stream>>>(boxes, scs, cnts, gpool2, out, N);
}